// Round 9
// baseline (212.047 us; speedup 1.0000x reference)
//
#include <hip/hip_runtime.h>
#include <math.h>

#define B_N 8
#define C_CH 128
#define H_IN 256
#define W_IN 256
#define HO 129
#define WO 129
#define SP (HO*WO)          // 16641
#define HIDDEN 11
#define NSTR 16             // vertical row-strips for dwt
#define SH 8                // output rows per strip
#define NGE 64              // cross-channel partial groups per batch
#define CPW 2               // channels per wave
#define WOP 132             // padded row stride for partials (even, 8B-aligned)
#define NBX 66              // combine spatial blocks per batch ((SP+255)/256)

__constant__ float c_lo[4] = {-0.12940952255126037f, 0.2241438680420134f,
                               0.8365163037378079f,  0.48296291314453416f};
__constant__ float c_hi[4] = {-0.48296291314453416f, 0.8365163037378079f,
                              -0.2241438680420134f, -0.12940952255126037f};

// Per-channel streaming state: scalar/float4 members only (SROA-safe).
struct CS {
  float4 cur0, cur1, nxt0, nxt1;
  float w00, w01, w02;
  float w10, w11, w12;
  float w20, w21, w22;
  float w30, w31, w32;
  float sA, mH;
};

// -------- Kernel 1: streaming DWT2, zero LDS, zero barriers -----------------
// CPW=2 halves per-wave state -> VGPR<=128 -> 4 waves/SIMD for latency cover.
__global__ __launch_bounds__(256, 4) void dwt_stream_kernel(
    const float* __restrict__ x,
    float* __restrict__ psum, float* __restrict__ pmax,
    float* __restrict__ chpsum, float* __restrict__ chpmax)
{
  const int bid  = blockIdx.x;            // ((b*16 + gb)*NSTR + s)
  const int s    = bid & (NSTR - 1);
  const int gb   = (bid >> 4) & 15;
  const int b    = bid >> 8;
  const int tid  = threadIdx.x;
  const int lane = tid & 63;
  const int wave = tid >> 6;
  const int g    = gb * 4 + wave;         // 0..63
  const int cb   = g * CPW;               // base channel
  const int j0   = s * SH;

  const float lo0 = c_lo[0], lo1 = c_lo[1], lo2 = c_lo[2], lo3 = c_lo[3];
  const float hi0 = c_hi[0], hi1 = c_hi[1], hi2 = c_hi[2], hi3 = c_hi[3];
  const float l03 = lo0 + lo3, l12 = lo1 + lo2;
  const float h03 = hi0 + hi3, h12 = hi1 + hi2;

  const float* xb0 = x + ((size_t)(b * C_CH + cb)) * (H_IN * W_IN) + 4 * lane;
  const float* xb1 = xb0 + (H_IN * W_IN);

  CS s0, s1;
#define INIT(S) do { \
    S.w00=0.f;S.w01=0.f;S.w02=0.f; S.w10=0.f;S.w11=0.f;S.w12=0.f; \
    S.w20=0.f;S.w21=0.f;S.w22=0.f; S.w30=0.f;S.w31=0.f;S.w32=0.f; \
    S.sA=0.f; S.mH=-INFINITY; } while(0)
  INIT(s0); INIT(s1);

  float* cps = chpsum + ((size_t)(b * NGE + g)) * (HO * WOP);
  float* cpm = chpmax + ((size_t)(b * NGE + g)) * (HO * WOP);

#define LOADC(S, XB, R) do { \
    const float* _p = (XB) + (R) * W_IN; \
    S.cur0 = *reinterpret_cast<const float4*>(_p); \
    S.cur1 = *reinterpret_cast<const float4*>(_p + W_IN); } while(0)

#define LOADN(S, XB, R) do { \
    const float* _p = (XB) + (R) * W_IN; \
    S.nxt0 = *reinterpret_cast<const float4*>(_p); \
    S.nxt1 = *reinterpret_cast<const float4*>(_p + W_IN); } while(0)

#define SWAPB(S) do { S.cur0 = S.nxt0; S.cur1 = S.nxt1; } while(0)

#define HROW(S, V) do { \
    float _pz = __shfl_up((V).z, 1); \
    float _pw = __shfl_up((V).w, 1); \
    float _l0 = (lane == 0) ? (l03 * (V).y + l12 * (V).x) \
                            : (lo0*(V).y + lo1*(V).x + lo2*_pw + lo3*_pz); \
    float _l1 = lo0*(V).w + lo1*(V).z + lo2*(V).y + lo3*(V).x; \
    float _l2 = l03 * (V).z + l12 * (V).w; \
    S.w00=S.w10; S.w10=S.w20; S.w20=S.w30; S.w30=_l0; \
    S.w01=S.w11; S.w11=S.w21; S.w21=S.w31; S.w31=_l1; \
    S.w02=S.w12; S.w12=S.w22; S.w22=S.w32; S.w32=_l2; } while(0)

#define EMITN(S) do { \
    float _a0 = lo0*S.w30 + lo1*S.w20 + lo2*S.w10 + lo3*S.w00; \
    float _h0 = hi0*S.w30 + hi1*S.w20 + hi2*S.w10 + hi3*S.w00; \
    float _a1 = lo0*S.w31 + lo1*S.w21 + lo2*S.w11 + lo3*S.w01; \
    float _h1 = hi0*S.w31 + hi1*S.w21 + hi2*S.w11 + hi3*S.w01; \
    float _a2 = lo0*S.w32 + lo1*S.w22 + lo2*S.w12 + lo3*S.w02; \
    float _h2 = hi0*S.w32 + hi1*S.w22 + hi2*S.w12 + hi3*S.w02; \
    S.sA += _a0 + _a1; S.mH = fmaxf(S.mH, fmaxf(_h0, _h1)); \
    if (lane == 63) { S.sA += _a2; S.mH = fmaxf(S.mH, _h2); } \
    cs0 += _a0 + _h0; cs1 += _a1 + _h1; cs2 += _a2 + _h2; \
    cm0 = fmaxf(cm0, fmaxf(_a0, _h0)); \
    cm1 = fmaxf(cm1, fmaxf(_a1, _h1)); \
    cm2 = fmaxf(cm2, fmaxf(_a2, _h2)); } while(0)

#define EMITT(S) do { \
    float _a0 = l03*S.w30 + l12*S.w20; float _h0 = h03*S.w30 + h12*S.w20; \
    float _a1 = l03*S.w31 + l12*S.w21; float _h1 = h03*S.w31 + h12*S.w21; \
    float _a2 = l03*S.w32 + l12*S.w22; float _h2 = h03*S.w32 + h12*S.w22; \
    S.sA += _a0 + _a1; S.mH = fmaxf(S.mH, fmaxf(_h0, _h1)); \
    if (lane == 63) { S.sA += _a2; S.mH = fmaxf(S.mH, _h2); } \
    cs0 += _a0 + _h0; cs1 += _a1 + _h1; cs2 += _a2 + _h2; \
    cm0 = fmaxf(cm0, fmaxf(_a0, _h0)); \
    cm1 = fmaxf(cm1, fmaxf(_a1, _h1)); \
    cm2 = fmaxf(cm2, fmaxf(_a2, _h2)); } while(0)

#define EMITB(S) do { \
    float _a0 = l03*S.w20 + l12*S.w30; float _h0 = h03*S.w20 + h12*S.w30; \
    float _a1 = l03*S.w21 + l12*S.w31; float _h1 = h03*S.w21 + h12*S.w31; \
    float _a2 = l03*S.w22 + l12*S.w32; float _h2 = h03*S.w22 + h12*S.w32; \
    S.sA += _a0 + _a1; S.mH = fmaxf(S.mH, fmaxf(_h0, _h1)); \
    if (lane == 63) { S.sA += _a2; S.mH = fmaxf(S.mH, _h2); } \
    cs0 += _a0 + _h0; cs1 += _a1 + _h1; cs2 += _a2 + _h2; \
    cm0 = fmaxf(cm0, fmaxf(_a0, _h0)); \
    cm1 = fmaxf(cm1, fmaxf(_a1, _h1)); \
    cm2 = fmaxf(cm2, fmaxf(_a2, _h2)); } while(0)

#define STORE_CROSS(JO) do { \
    float* _ps = cps + (size_t)(JO) * WOP; \
    float* _pm = cpm + (size_t)(JO) * WOP; \
    *reinterpret_cast<float2*>(_ps + 2 * lane) = make_float2(cs0, cs1); \
    *reinterpret_cast<float2*>(_pm + 2 * lane) = make_float2(cm0, cm1); \
    if (lane == 63) { _ps[128] = cs2; _pm[128] = cm2; } } while(0)

  // ---- software-pipelined stream ----
  const int rstart = (s == 0) ? 0 : (2 * j0 - 2);
  const int npairs = (s == 0) ? SH : (SH + 1);   // s>0: pair 0 = halo warm-up

  LOADC(s0, xb0, rstart); LOADC(s1, xb1, rstart);

  for (int p = 0; p < npairs; ++p) {
    const bool last = (p + 1 == npairs);
    if (!last) {
      const int rn = rstart + 2 * (p + 1);
      LOADN(s0, xb0, rn); LOADN(s1, xb1, rn);
    }

    HROW(s0, s0.cur0); HROW(s0, s0.cur1);
    HROW(s1, s1.cur0); HROW(s1, s1.cur1);

    if (s == 0 || p > 0) {
      float cs0 = 0.f, cs1 = 0.f, cs2 = 0.f;
      float cm0 = -INFINITY, cm1 = -INFINITY, cm2 = -INFINITY;
      int jo;
      if (s == 0 && p == 0) {
        EMITT(s0); EMITT(s1);
        jo = 0;
      } else {
        EMITN(s0); EMITN(s1);
        jo = (s == 0) ? p : (j0 + p - 1);
      }
      STORE_CROSS(jo);
    }

    if (!last) { SWAPB(s0); SWAPB(s1); }
  }

  if (s == NSTR - 1) {
    float cs0 = 0.f, cs1 = 0.f, cs2 = 0.f;
    float cm0 = -INFINITY, cm1 = -INFINITY, cm2 = -INFINITY;
    EMITB(s0); EMITB(s1);
    STORE_CROSS(128);
  }

  // ---- per-channel strip reduction (wave-local, deterministic) ----
#define REDUCE_CH(S, CH) do { \
    float _ss = S.sA, _sm = S.mH; \
    for (int off = 32; off > 0; off >>= 1) { \
      _ss += __shfl_down(_ss, off, 64); \
      _sm = fmaxf(_sm, __shfl_down(_sm, off, 64)); \
    } \
    if (lane == 0) { \
      size_t _bc = (size_t)(b * C_CH + cb + (CH)); \
      psum[_bc * NSTR + s] = _ss; \
      pmax[_bc * NSTR + s] = _sm; \
    } } while(0)

  REDUCE_CH(s0, 0); REDUCE_CH(s1, 1);
}

// -------- Kernel 2: combine group partials -> sa_in; +fused MLP column ------
__global__ __launch_bounds__(256) void combine_kernel(
    const float* __restrict__ chpsum, const float* __restrict__ chpmax,
    float* __restrict__ sa_in,
    const float* __restrict__ psum, const float* __restrict__ pmax,
    const float* __restrict__ w1, const float* __restrict__ b1,
    const float* __restrict__ w2, const float* __restrict__ b2,
    float* __restrict__ att)
{
  int b = blockIdx.y;
  int bx = blockIdx.x;
  int t = threadIdx.x;

  if (bx == NBX) {
    // fused channel-attention MLP (one block per batch; threads 0..127)
    __shared__ float p[C_CH];
    __shared__ float h[HIDDEN];
    int c = t;
    if (c < C_CH) {
      float s = 0.f, m = -INFINITY;
      #pragma unroll
      for (int k = 0; k < NSTR; ++k) {
        s += psum[(b * C_CH + c) * NSTR + k];
        m = fmaxf(m, pmax[(b * C_CH + c) * NSTR + k]);
      }
      p[c] = s * (1.f / 16641.f) + m;
    }
    __syncthreads();
    if (c < HIDDEN) {
      float acc = b1[c];
      for (int k = 0; k < C_CH; ++k) acc += p[k] * w1[k * HIDDEN + c];
      h[c] = fmaxf(acc, 0.f);
    }
    __syncthreads();
    if (c < C_CH) {
      float acc = b2[c];
      #pragma unroll
      for (int j = 0; j < HIDDEN; ++j) acc += h[j] * w2[j * C_CH + c];
      att[b * C_CH + c] = 1.f / (1.f + expf(-acc));
    }
    return;
  }

  int s = bx * 256 + t;
  if (s >= SP) return;
  int jo  = s / WO;
  int col = s - jo * WO;
  size_t off = (size_t)jo * WOP + col;
  float sum = 0.f, mx = -INFINITY;
  #pragma unroll 4
  for (int gg = 0; gg < NGE; ++gg) {
    sum += chpsum[((size_t)(b * NGE + gg)) * (HO * WOP) + off];
    mx = fmaxf(mx, chpmax[((size_t)(b * NGE + gg)) * (HO * WOP) + off]);
  }
  sa_in[(size_t)b * 2 * SP + s]      = sum * (1.f / 256.f);
  sa_in[(size_t)b * 2 * SP + SP + s] = mx;
}

// -------- Kernel 3: 5x5 conv (2->1 ch, zero pad) + sigmoid ------------------
__global__ __launch_bounds__(256) void conv_kernel(
    const float* __restrict__ sa_in, const float* __restrict__ w_sa,
    float* __restrict__ sa)
{
  int b = blockIdx.y;
  int s = blockIdx.x * 256 + threadIdx.x;
  if (s >= SP) return;
  int i = s / WO;
  int j = s - i * WO;
  float acc = 0.f;
  const float* in0 = sa_in + (size_t)b * 2 * SP;
  #pragma unroll
  for (int ch = 0; ch < 2; ++ch) {
    const float* in = in0 + ch * SP;
    #pragma unroll
    for (int u = 0; u < 5; ++u) {
      int ii = i + u - 2;
      if (ii < 0 || ii >= HO) continue;
      #pragma unroll
      for (int v = 0; v < 5; ++v) {
        int jj = j + v - 2;
        if (jj < 0 || jj >= WO) continue;
        acc += in[ii * WO + jj] * w_sa[(ch * 5 + u) * 5 + v];
      }
    }
  }
  sa[(size_t)b * SP + s] = 1.f / (1.f + expf(-acc));
}

// -------- Kernel 4: out = x * att[b,c] * bilinear(sa) (fused resize) --------
__global__ __launch_bounds__(256) void final3_kernel(
    const float* __restrict__ x, const float* __restrict__ att,
    const float* __restrict__ sa, float* __restrict__ out)
{
  // bid = ((b*64 + rg)*4 + cchunk); block: 4 rows x 256 cols x 32 channels
  int bid = blockIdx.x;
  int cchunk = bid & 3;
  int rg  = (bid >> 2) & 63;
  int b   = bid >> 8;
  int t = threadIdx.x;
  int r = t >> 6;          // 0..3
  int col4 = t & 63;
  int I = rg * 4 + r;

  __shared__ float att_s[32];
  __shared__ float sa_s[4][WOP];
  if (t < 32) att_s[t] = att[b * C_CH + cchunk * 32 + t];

  // stage the (<=4) sa rows this block's 4 output rows interpolate from
  float ti0 = fminf(fmaxf((rg * 4 + 0.5f) * (129.f / 256.f) - 0.5f, 0.f), 128.f);
  int ilo = (int)ti0;      // block-uniform
  const float* sab = sa + (size_t)b * SP;
  if (t < WO) {
    #pragma unroll
    for (int rr = 0; rr < 4; ++rr) {
      int ir = min(ilo + rr, 128);
      sa_s[rr][t] = sab[ir * WO + t];
    }
  }
  __syncthreads();

  // per-thread bilinear (identical math to the standalone resize kernel)
  float ti = fminf(fmaxf((I + 0.5f) * (129.f / 256.f) - 0.5f, 0.f), 128.f);
  int i0 = (int)ti;
  float fi = ti - (float)i0;
  int i0r = i0 - ilo;
  int i1r = min(i0 + 1, 128) - ilo;

  float res[4];
  #pragma unroll
  for (int q = 0; q < 4; ++q) {
    int J = col4 * 4 + q;
    float tj = fminf(fmaxf((J + 0.5f) * (129.f / 256.f) - 0.5f, 0.f), 128.f);
    int jj0 = (int)tj;
    float fj = tj - (float)jj0;
    int jj1 = min(jj0 + 1, 128);
    float v0 = sa_s[i0r][jj0] + fj * (sa_s[i0r][jj1] - sa_s[i0r][jj0]);
    float v1 = sa_s[i1r][jj0] + fj * (sa_s[i1r][jj1] - sa_s[i1r][jj0]);
    res[q] = v0 + fi * (v1 - v0);
  }

  size_t base4 = ((size_t)(b * C_CH + cchunk * 32) * 256 + I) * 64 + col4;
  const float4* xp = reinterpret_cast<const float4*>(x);
  float4* op = reinterpret_cast<float4*>(out);
  #pragma unroll 4
  for (int cc = 0; cc < 32; ++cc) {
    float a = att_s[cc];
    float4 xv = xp[base4 + (size_t)cc * 16384];
    float4 ov;
    ov.x = xv.x * a * res[0];
    ov.y = xv.y * a * res[1];
    ov.z = xv.z * a * res[2];
    ov.w = xv.w * a * res[3];
    op[base4 + (size_t)cc * 16384] = ov;
  }
}

extern "C" void kernel_launch(void* const* d_in, const int* in_sizes, int n_in,
                              void* d_out, int out_size, void* d_ws, size_t ws_size,
                              hipStream_t stream) {
  const float* x    = (const float*)d_in[0];
  const float* w1   = (const float*)d_in[1];
  const float* b1   = (const float*)d_in[2];
  const float* w2   = (const float*)d_in[3];
  const float* b2   = (const float*)d_in[4];
  const float* w_sa = (const float*)d_in[5];
  float* out = (float*)d_out;

  // workspace layout (floats)
  float* chpsum = (float*)d_ws;                            // B*NGE*HO*WOP
  float* chpmax = chpsum + (size_t)B_N * NGE * HO * WOP;   // B*NGE*HO*WOP
  float* psum   = chpmax + (size_t)B_N * NGE * HO * WOP;   // B*C*NSTR
  float* pmax   = psum + B_N * C_CH * NSTR;                // B*C*NSTR
  float* sa_in  = pmax + B_N * C_CH * NSTR;                // B*2*SP
  float* att    = sa_in + (size_t)B_N * 2 * SP;            // B*C
  float* sa     = att + B_N * C_CH;                        // B*SP

  hipLaunchKernelGGL(dwt_stream_kernel, dim3(B_N * 16 * NSTR), dim3(256), 0, stream,
                     x, psum, pmax, chpsum, chpmax);
  hipLaunchKernelGGL(combine_kernel, dim3(NBX + 1, B_N), dim3(256), 0, stream,
                     chpsum, chpmax, sa_in, psum, pmax, w1, b1, w2, b2, att);
  hipLaunchKernelGGL(conv_kernel, dim3((SP + 255) / 256, B_N), dim3(256), 0, stream,
                     sa_in, w_sa, sa);
  hipLaunchKernelGGL(final3_kernel, dim3(B_N * 64 * 4), dim3(256), 0, stream,
                     x, att, sa, out);
}

// Round 12
// 190.612 us; speedup vs baseline: 1.1125x; 1.1125x over previous
//
#include <hip/hip_runtime.h>
#include <math.h>

#define B_N 8
#define C_CH 128
#define H_IN 256
#define W_IN 256
#define HO 129
#define WO 129
#define SP (HO*WO)          // 16641
#define HIDDEN 11
#define NSTR 16             // vertical row-strips for dwt
#define SH 8                // output rows per strip
#define NGE 32              // cross-channel partial groups per batch
#define CPW 4               // channels per wave
#define WOP 132             // padded row stride for partials (even, 8B-aligned)
#define NBX 66              // combine spatial blocks per batch ((SP+255)/256)

typedef float f4 __attribute__((ext_vector_type(4)));
#define NTLOAD4(P) __builtin_nontemporal_load(reinterpret_cast<const f4*>(P))

__constant__ float c_lo[4] = {-0.12940952255126037f, 0.2241438680420134f,
                               0.8365163037378079f,  0.48296291314453416f};
__constant__ float c_hi[4] = {-0.48296291314453416f, 0.8365163037378079f,
                              -0.2241438680420134f, -0.12940952255126037f};

// Per-channel streaming state: scalar/f4 members only (SROA-safe).
struct CS {
  f4 cur0, cur1, nxt0, nxt1;
  float w00, w01, w02;
  float w10, w11, w12;
  float w20, w21, w22;
  float w30, w31, w32;
  float sA, mH;
};

// -------- Kernel 1: streaming DWT2, zero LDS, zero barriers -----------------
// R8 structure (CPW=4, no min-occupancy bound); x loads are NON-TEMPORAL
// (read-once stream — keep L2/L3 for the partial buffers instead).
__global__ __launch_bounds__(256) void dwt_stream_kernel(
    const float* __restrict__ x,
    float* __restrict__ psum, float* __restrict__ pmax,
    float* __restrict__ chpsum, float* __restrict__ chpmax)
{
  const int bid  = blockIdx.x;            // ((b*8 + gb)*NSTR + s)
  const int s    = bid & (NSTR - 1);
  const int gb   = (bid >> 4) & 7;
  const int b    = bid >> 7;
  const int tid  = threadIdx.x;
  const int lane = tid & 63;
  const int wave = tid >> 6;
  const int g    = gb * 4 + wave;         // 0..31
  const int cb   = g * CPW;               // base channel
  const int j0   = s * SH;

  const float lo0 = c_lo[0], lo1 = c_lo[1], lo2 = c_lo[2], lo3 = c_lo[3];
  const float hi0 = c_hi[0], hi1 = c_hi[1], hi2 = c_hi[2], hi3 = c_hi[3];
  const float l03 = lo0 + lo3, l12 = lo1 + lo2;
  const float h03 = hi0 + hi3, h12 = hi1 + hi2;

  const float* xb0 = x + ((size_t)(b * C_CH + cb)) * (H_IN * W_IN) + 4 * lane;
  const float* xb1 = xb0 + (H_IN * W_IN);
  const float* xb2 = xb1 + (H_IN * W_IN);
  const float* xb3 = xb2 + (H_IN * W_IN);

  CS s0, s1, s2, s3;
#define INIT(S) do { \
    S.w00=0.f;S.w01=0.f;S.w02=0.f; S.w10=0.f;S.w11=0.f;S.w12=0.f; \
    S.w20=0.f;S.w21=0.f;S.w22=0.f; S.w30=0.f;S.w31=0.f;S.w32=0.f; \
    S.sA=0.f; S.mH=-INFINITY; } while(0)
  INIT(s0); INIT(s1); INIT(s2); INIT(s3);

  float* cps = chpsum + ((size_t)(b * NGE + g)) * (HO * WOP);
  float* cpm = chpmax + ((size_t)(b * NGE + g)) * (HO * WOP);

#define LOADC(S, XB, R) do { \
    const float* _p = (XB) + (R) * W_IN; \
    S.cur0 = NTLOAD4(_p); \
    S.cur1 = NTLOAD4(_p + W_IN); } while(0)

#define LOADN(S, XB, R) do { \
    const float* _p = (XB) + (R) * W_IN; \
    S.nxt0 = NTLOAD4(_p); \
    S.nxt1 = NTLOAD4(_p + W_IN); } while(0)

#define SWAPB(S) do { S.cur0 = S.nxt0; S.cur1 = S.nxt1; } while(0)

#define HROW(S, V) do { \
    float _pz = __shfl_up((V).z, 1); \
    float _pw = __shfl_up((V).w, 1); \
    float _l0 = (lane == 0) ? (l03 * (V).y + l12 * (V).x) \
                            : (lo0*(V).y + lo1*(V).x + lo2*_pw + lo3*_pz); \
    float _l1 = lo0*(V).w + lo1*(V).z + lo2*(V).y + lo3*(V).x; \
    float _l2 = l03 * (V).z + l12 * (V).w; \
    S.w00=S.w10; S.w10=S.w20; S.w20=S.w30; S.w30=_l0; \
    S.w01=S.w11; S.w11=S.w21; S.w21=S.w31; S.w31=_l1; \
    S.w02=S.w12; S.w12=S.w22; S.w22=S.w32; S.w32=_l2; } while(0)

#define EMITN(S) do { \
    float _a0 = lo0*S.w30 + lo1*S.w20 + lo2*S.w10 + lo3*S.w00; \
    float _h0 = hi0*S.w30 + hi1*S.w20 + hi2*S.w10 + hi3*S.w00; \
    float _a1 = lo0*S.w31 + lo1*S.w21 + lo2*S.w11 + lo3*S.w01; \
    float _h1 = hi0*S.w31 + hi1*S.w21 + hi2*S.w11 + hi3*S.w01; \
    float _a2 = lo0*S.w32 + lo1*S.w22 + lo2*S.w12 + lo3*S.w02; \
    float _h2 = hi0*S.w32 + hi1*S.w22 + hi2*S.w12 + hi3*S.w02; \
    S.sA += _a0 + _a1; S.mH = fmaxf(S.mH, fmaxf(_h0, _h1)); \
    if (lane == 63) { S.sA += _a2; S.mH = fmaxf(S.mH, _h2); } \
    cs0 += _a0 + _h0; cs1 += _a1 + _h1; cs2 += _a2 + _h2; \
    cm0 = fmaxf(cm0, fmaxf(_a0, _h0)); \
    cm1 = fmaxf(cm1, fmaxf(_a1, _h1)); \
    cm2 = fmaxf(cm2, fmaxf(_a2, _h2)); } while(0)

#define EMITT(S) do { \
    float _a0 = l03*S.w30 + l12*S.w20; float _h0 = h03*S.w30 + h12*S.w20; \
    float _a1 = l03*S.w31 + l12*S.w21; float _h1 = h03*S.w31 + h12*S.w21; \
    float _a2 = l03*S.w32 + l12*S.w22; float _h2 = h03*S.w32 + h12*S.w22; \
    S.sA += _a0 + _a1; S.mH = fmaxf(S.mH, fmaxf(_h0, _h1)); \
    if (lane == 63) { S.sA += _a2; S.mH = fmaxf(S.mH, _h2); } \
    cs0 += _a0 + _h0; cs1 += _a1 + _h1; cs2 += _a2 + _h2; \
    cm0 = fmaxf(cm0, fmaxf(_a0, _h0)); \
    cm1 = fmaxf(cm1, fmaxf(_a1, _h1)); \
    cm2 = fmaxf(cm2, fmaxf(_a2, _h2)); } while(0)

#define EMITB(S) do { \
    float _a0 = l03*S.w20 + l12*S.w30; float _h0 = h03*S.w20 + h12*S.w30; \
    float _a1 = l03*S.w21 + l12*S.w31; float _h1 = h03*S.w21 + h12*S.w31; \
    float _a2 = l03*S.w22 + l12*S.w32; float _h2 = h03*S.w22 + h12*S.w32; \
    S.sA += _a0 + _a1; S.mH = fmaxf(S.mH, fmaxf(_h0, _h1)); \
    if (lane == 63) { S.sA += _a2; S.mH = fmaxf(S.mH, _h2); } \
    cs0 += _a0 + _h0; cs1 += _a1 + _h1; cs2 += _a2 + _h2; \
    cm0 = fmaxf(cm0, fmaxf(_a0, _h0)); \
    cm1 = fmaxf(cm1, fmaxf(_a1, _h1)); \
    cm2 = fmaxf(cm2, fmaxf(_a2, _h2)); } while(0)

#define STORE_CROSS(JO) do { \
    float* _ps = cps + (size_t)(JO) * WOP; \
    float* _pm = cpm + (size_t)(JO) * WOP; \
    *reinterpret_cast<float2*>(_ps + 2 * lane) = make_float2(cs0, cs1); \
    *reinterpret_cast<float2*>(_pm + 2 * lane) = make_float2(cm0, cm1); \
    if (lane == 63) { _ps[128] = cs2; _pm[128] = cm2; } } while(0)

  // ---- software-pipelined stream ----
  const int rstart = (s == 0) ? 0 : (2 * j0 - 2);
  const int npairs = (s == 0) ? SH : (SH + 1);   // s>0: pair 0 = halo warm-up

  LOADC(s0, xb0, rstart); LOADC(s1, xb1, rstart);
  LOADC(s2, xb2, rstart); LOADC(s3, xb3, rstart);

  for (int p = 0; p < npairs; ++p) {
    const bool last = (p + 1 == npairs);
    if (!last) {
      const int rn = rstart + 2 * (p + 1);
      LOADN(s0, xb0, rn); LOADN(s1, xb1, rn);
      LOADN(s2, xb2, rn); LOADN(s3, xb3, rn);
    }

    HROW(s0, s0.cur0); HROW(s0, s0.cur1);
    HROW(s1, s1.cur0); HROW(s1, s1.cur1);
    HROW(s2, s2.cur0); HROW(s2, s2.cur1);
    HROW(s3, s3.cur0); HROW(s3, s3.cur1);

    if (s == 0 || p > 0) {
      float cs0 = 0.f, cs1 = 0.f, cs2 = 0.f;
      float cm0 = -INFINITY, cm1 = -INFINITY, cm2 = -INFINITY;
      int jo;
      if (s == 0 && p == 0) {
        EMITT(s0); EMITT(s1); EMITT(s2); EMITT(s3);
        jo = 0;
      } else {
        EMITN(s0); EMITN(s1); EMITN(s2); EMITN(s3);
        jo = (s == 0) ? p : (j0 + p - 1);
      }
      STORE_CROSS(jo);
    }

    if (!last) { SWAPB(s0); SWAPB(s1); SWAPB(s2); SWAPB(s3); }
  }

  if (s == NSTR - 1) {
    float cs0 = 0.f, cs1 = 0.f, cs2 = 0.f;
    float cm0 = -INFINITY, cm1 = -INFINITY, cm2 = -INFINITY;
    EMITB(s0); EMITB(s1); EMITB(s2); EMITB(s3);
    STORE_CROSS(128);
  }

  // ---- per-channel strip reduction (wave-local, deterministic) ----
#define REDUCE_CH(S, CH) do { \
    float _ss = S.sA, _sm = S.mH; \
    for (int off = 32; off > 0; off >>= 1) { \
      _ss += __shfl_down(_ss, off, 64); \
      _sm = fmaxf(_sm, __shfl_down(_sm, off, 64)); \
    } \
    if (lane == 0) { \
      size_t _bc = (size_t)(b * C_CH + cb + (CH)); \
      psum[_bc * NSTR + s] = _ss; \
      pmax[_bc * NSTR + s] = _sm; \
    } } while(0)

  REDUCE_CH(s0, 0); REDUCE_CH(s1, 1); REDUCE_CH(s2, 2); REDUCE_CH(s3, 3);
}

// -------- Kernel 2: combine group partials -> sa_in; +fused MLP column ------
__global__ __launch_bounds__(256) void combine_kernel(
    const float* __restrict__ chpsum, const float* __restrict__ chpmax,
    float* __restrict__ sa_in,
    const float* __restrict__ psum, const float* __restrict__ pmax,
    const float* __restrict__ w1, const float* __restrict__ b1,
    const float* __restrict__ w2, const float* __restrict__ b2,
    float* __restrict__ att)
{
  int b = blockIdx.y;
  int bx = blockIdx.x;
  int t = threadIdx.x;

  if (bx == NBX) {
    // fused channel-attention MLP (one block per batch; threads 0..127)
    __shared__ float p[C_CH];
    __shared__ float h[HIDDEN];
    int c = t;
    if (c < C_CH) {
      float s = 0.f, m = -INFINITY;
      #pragma unroll
      for (int k = 0; k < NSTR; ++k) {
        s += psum[(b * C_CH + c) * NSTR + k];
        m = fmaxf(m, pmax[(b * C_CH + c) * NSTR + k]);
      }
      p[c] = s * (1.f / 16641.f) + m;
    }
    __syncthreads();
    if (c < HIDDEN) {
      float acc = b1[c];
      for (int k = 0; k < C_CH; ++k) acc += p[k] * w1[k * HIDDEN + c];
      h[c] = fmaxf(acc, 0.f);
    }
    __syncthreads();
    if (c < C_CH) {
      float acc = b2[c];
      #pragma unroll
      for (int j = 0; j < HIDDEN; ++j) acc += h[j] * w2[j * C_CH + c];
      att[b * C_CH + c] = 1.f / (1.f + expf(-acc));
    }
    return;
  }

  int s = bx * 256 + t;
  if (s >= SP) return;
  int jo  = s / WO;
  int col = s - jo * WO;
  size_t off = (size_t)jo * WOP + col;
  float sum = 0.f, mx = -INFINITY;
  #pragma unroll 4
  for (int gg = 0; gg < NGE; ++gg) {
    sum += chpsum[((size_t)(b * NGE + gg)) * (HO * WOP) + off];
    mx = fmaxf(mx, chpmax[((size_t)(b * NGE + gg)) * (HO * WOP) + off]);
  }
  sa_in[(size_t)b * 2 * SP + s]      = sum * (1.f / 256.f);
  sa_in[(size_t)b * 2 * SP + SP + s] = mx;
}

// -------- Kernel 3: 5x5 conv (2->1 ch, zero pad) + sigmoid ------------------
__global__ __launch_bounds__(256) void conv_kernel(
    const float* __restrict__ sa_in, const float* __restrict__ w_sa,
    float* __restrict__ sa)
{
  int b = blockIdx.y;
  int s = blockIdx.x * 256 + threadIdx.x;
  if (s >= SP) return;
  int i = s / WO;
  int j = s - i * WO;
  float acc = 0.f;
  const float* in0 = sa_in + (size_t)b * 2 * SP;
  #pragma unroll
  for (int ch = 0; ch < 2; ++ch) {
    const float* in = in0 + ch * SP;
    #pragma unroll
    for (int u = 0; u < 5; ++u) {
      int ii = i + u - 2;
      if (ii < 0 || ii >= HO) continue;
      #pragma unroll
      for (int v = 0; v < 5; ++v) {
        int jj = j + v - 2;
        if (jj < 0 || jj >= WO) continue;
        acc += in[ii * WO + jj] * w_sa[(ch * 5 + u) * 5 + v];
      }
    }
  }
  sa[(size_t)b * SP + s] = 1.f / (1.f + expf(-acc));
}

// -------- Kernel 4: bilinear resize sa (8,129,129) -> sar (8,256,256) -------
__global__ __launch_bounds__(256) void resize_kernel(
    const float* __restrict__ sa, float* __restrict__ sar)
{
  int idx = blockIdx.x * 256 + threadIdx.x;   // 8*256*256 = 524288
  int J = idx & 255;
  int I = (idx >> 8) & 255;
  int b = idx >> 16;

  float ti = (I + 0.5f) * (129.f / 256.f) - 0.5f;
  ti = fminf(fmaxf(ti, 0.f), 128.f);
  int i0 = (int)ti;
  float fi = ti - (float)i0;
  int i1 = min(i0 + 1, 128);

  float tj = (J + 0.5f) * (129.f / 256.f) - 0.5f;
  tj = fminf(fmaxf(tj, 0.f), 128.f);
  int jj0 = (int)tj;
  float fj = tj - (float)jj0;
  int jj1 = min(jj0 + 1, 128);

  const float* r0 = sa + ((size_t)b * HO + i0) * WO;
  const float* r1 = sa + ((size_t)b * HO + i1) * WO;
  float v0 = r0[jj0] + fj * (r0[jj1] - r0[jj0]);
  float v1 = r1[jj0] + fj * (r1[jj1] - r1[jj0]);
  sar[idx] = v0 + fi * (v1 - v0);
}

// -------- Kernel 5: out = x * att[b,c] * sar (pure stream, nt x/out) --------
__global__ __launch_bounds__(256) void final2_kernel(
    const float* __restrict__ x, const float* __restrict__ att,
    const float* __restrict__ sar, float* __restrict__ out)
{
  // bid = ((b*64 + rg)*4 + cchunk); block: 4 rows x 256 cols x 32 channels
  int bid = blockIdx.x;
  int cchunk = bid & 3;
  int rg  = (bid >> 2) & 63;
  int b   = bid >> 8;
  int t = threadIdx.x;
  int r = t >> 6;          // 0..3
  int col4 = t & 63;
  int I = rg * 4 + r;

  __shared__ float att_s[32];
  if (t < 32) att_s[t] = att[b * C_CH + cchunk * 32 + t];
  __syncthreads();

  f4 sv = *reinterpret_cast<const f4*>(sar + ((size_t)b * 256 + I) * 256 + 4 * col4);

  size_t base4 = ((size_t)(b * C_CH + cchunk * 32) * 256 + I) * 64 + col4;
  const float* xp = x;
  float* op = out;
  #pragma unroll 4
  for (int cc = 0; cc < 32; ++cc) {
    float a = att_s[cc];
    size_t e = (base4 + (size_t)cc * 16384) * 4;
    f4 xv = NTLOAD4(xp + e);
    f4 ov;
    ov.x = xv.x * a * sv.x;
    ov.y = xv.y * a * sv.y;
    ov.z = xv.z * a * sv.z;
    ov.w = xv.w * a * sv.w;
    __builtin_nontemporal_store(ov, reinterpret_cast<f4*>(op + e));
  }
}

extern "C" void kernel_launch(void* const* d_in, const int* in_sizes, int n_in,
                              void* d_out, int out_size, void* d_ws, size_t ws_size,
                              hipStream_t stream) {
  const float* x    = (const float*)d_in[0];
  const float* w1   = (const float*)d_in[1];
  const float* b1   = (const float*)d_in[2];
  const float* w2   = (const float*)d_in[3];
  const float* b2   = (const float*)d_in[4];
  const float* w_sa = (const float*)d_in[5];
  float* out = (float*)d_out;

  // workspace layout (floats)
  float* chpsum = (float*)d_ws;                            // B*NGE*HO*WOP
  float* chpmax = chpsum + (size_t)B_N * NGE * HO * WOP;   // B*NGE*HO*WOP
  float* psum   = chpmax + (size_t)B_N * NGE * HO * WOP;   // B*C*NSTR
  float* pmax   = psum + B_N * C_CH * NSTR;                // B*C*NSTR
  float* sa_in  = pmax + B_N * C_CH * NSTR;                // B*2*SP
  float* att    = sa_in + (size_t)B_N * 2 * SP;            // B*C
  float* sa     = att + B_N * C_CH;                        // B*SP
  float* sar    = sa + (size_t)B_N * SP;                   // B*256*256

  hipLaunchKernelGGL(dwt_stream_kernel, dim3(B_N * 8 * NSTR), dim3(256), 0, stream,
                     x, psum, pmax, chpsum, chpmax);
  hipLaunchKernelGGL(combine_kernel, dim3(NBX + 1, B_N), dim3(256), 0, stream,
                     chpsum, chpmax, sa_in, psum, pmax, w1, b1, w2, b2, att);
  hipLaunchKernelGGL(conv_kernel, dim3((SP + 255) / 256, B_N), dim3(256), 0, stream,
                     sa_in, w_sa, sa);
  hipLaunchKernelGGL(resize_kernel, dim3(B_N * H_IN * W_IN / 256), dim3(256), 0, stream,
                     sa, sar);
  hipLaunchKernelGGL(final2_kernel, dim3(B_N * 64 * 4), dim3(256), 0, stream,
                     x, att, sar, out);
}